// Round 1
// baseline (239.784 us; speedup 1.0000x reference)
//
#include <hip/hip_runtime.h>
#include <stdint.h>

#define H_    16
#define HKV_  4
#define D_    128
#define S_    2048
#define HID_  2048
#define RLEN_ 2048

typedef unsigned short u16;
typedef __attribute__((ext_vector_type(4))) float f32x4;
typedef __attribute__((ext_vector_type(8))) __bf16 bf16x8;
typedef __attribute__((ext_vector_type(4))) unsigned short u16x4;

__device__ __forceinline__ u16 f2bf(float f) {
  union { float f; unsigned u; } v; v.f = f;
  unsigned r = v.u + 0x7FFFu + ((v.u >> 16) & 1u);
  return (u16)(r >> 16);
}
__device__ __forceinline__ float bf2f(u16 h) {
  union { unsigned u; float f; } v; v.u = ((unsigned)h) << 16;
  return v.f;
}

#define GLL(srcp, ldsp) \
  __builtin_amdgcn_global_load_lds((const __attribute__((address_space(1))) unsigned int*)(srcp), \
                                   (__attribute__((address_space(3))) unsigned int*)(ldsp), 16, 0, 0)

// ---------------- fp32 -> bf16 elementwise ----------------
__global__ void k_cvt(const float* __restrict__ in, u16* __restrict__ out, int n4) {
  int i = blockIdx.x * 256 + threadIdx.x;
  if (i >= n4) return;
  float4 v = ((const float4*)in)[i];
  u16x4 o;
  o.x = f2bf(v.x); o.y = f2bf(v.y); o.z = f2bf(v.z); o.w = f2bf(v.w);
  ((u16x4*)out)[i] = o;
}

// ---------------- fp32 (K x N) -> bf16 transposed (N x K) ----------------
__global__ void k_transw(const float* __restrict__ in, u16* __restrict__ out, int K, int N) {
  __shared__ float tile[32][33];
  int bx = blockIdx.x * 32, by = blockIdx.y * 32;
  int tx = threadIdx.x, ty = threadIdx.y;  // 32 x 8
#pragma unroll
  for (int i = 0; i < 32; i += 8)
    tile[ty + i][tx] = in[(size_t)(by + ty + i) * N + bx + tx];
  __syncthreads();
#pragma unroll
  for (int i = 0; i < 32; i += 8)
    out[(size_t)(bx + ty + i) * K + by + tx] = f2bf(tile[tx][ty + i]);
}

// ---------------- bf16 GEMM: C = A(MxK) * Bt(NxK)^T ; m97 structure ----------------
template <int OUTF32>
__global__ __launch_bounds__(256) void k_gemm(const u16* __restrict__ A, const u16* __restrict__ Bt,
                                              float* __restrict__ Cf, u16* __restrict__ Cb,
                                              int M, int N, int K) {
  __shared__ __attribute__((aligned(16))) u16 As[128 * 32];
  __shared__ __attribute__((aligned(16))) u16 Bs[128 * 32];
  const int bm = blockIdx.y * 128, bn = blockIdx.x * 128;
  const int tid = threadIdx.x, wave = tid >> 6, lane = tid & 63;
  const int wr = wave >> 1, wc = wave & 1;
  const int l15 = lane & 15, lhi = lane >> 4;
  f32x4 acc[4][4] = {};
  const u16* pA  = A  + (size_t)(bm + (tid >> 2)) * K + (tid & 3) * 8;
  const u16* pA2 = A  + (size_t)(bm + 64 + (tid >> 2)) * K + (tid & 3) * 8;
  const u16* pB  = Bt + (size_t)(bn + (tid >> 2)) * K + (tid & 3) * 8;
  const u16* pB2 = Bt + (size_t)(bn + 64 + (tid >> 2)) * K + (tid & 3) * 8;

  for (int k0 = 0; k0 < K; k0 += 32) {
    __syncthreads();
    GLL(pA + k0,  As + wave * 512);
    GLL(pA2 + k0, As + 2048 + wave * 512);
    GLL(pB + k0,  Bs + wave * 512);
    GLL(pB2 + k0, Bs + 2048 + wave * 512);
    __syncthreads();
    bf16x8 af[4], bfr[4];
#pragma unroll
    for (int m = 0; m < 4; m++)
      af[m] = *(const bf16x8*)(As + (wr * 64 + m * 16 + l15) * 32 + lhi * 8);
#pragma unroll
    for (int n = 0; n < 4; n++)
      bfr[n] = *(const bf16x8*)(Bs + (wc * 64 + n * 16 + l15) * 32 + lhi * 8);
#pragma unroll
    for (int m = 0; m < 4; m++)
#pragma unroll
      for (int n = 0; n < 4; n++)
        acc[m][n] = __builtin_amdgcn_mfma_f32_16x16x32_bf16(af[m], bfr[n], acc[m][n], 0, 0, 0);
  }
  const int r0 = bm + wr * 64, c0 = bn + wc * 64;
#pragma unroll
  for (int m = 0; m < 4; m++)
#pragma unroll
    for (int n = 0; n < 4; n++) {
      int r = r0 + m * 16 + lhi * 4, cc = c0 + n * 16 + l15;
#pragma unroll
      for (int j = 0; j < 4; j++) {
        if (OUTF32) Cf[(size_t)(r + j) * N + cc] = acc[m][n][j];
        else        Cb[(size_t)(r + j) * N + cc] = f2bf(acc[m][n][j]);
      }
    }
}

// ---------------- RoPE for Q (scale folded in), plain [H][S][D] layout ----------------
__global__ void k_ropeq(const u16* __restrict__ qkv, const float* __restrict__ cs,
                        const float* __restrict__ sn, u16* __restrict__ Q) {
  int tid = threadIdx.x;
  int idx = blockIdx.x * 4 + (tid >> 6);
  int d = tid & 63;
  int h = idx >> 11, s = idx & (S_ - 1);
  const u16* x = qkv + (size_t)s * 3072 + h * 128;
  float x1 = bf2f(x[d]), x2 = bf2f(x[d + 64]);
  float c1 = cs[s * D_ + d], s1v = sn[s * D_ + d];
  float c2 = cs[s * D_ + d + 64], s2v = sn[s * D_ + d + 64];
  const float sc = 0.08838834764831845f;  // D^-0.5
  u16* o = Q + ((size_t)h * S_ + s) * D_;
  o[d]      = f2bf((x1 * c1 - x2 * s1v) * sc);
  o[d + 64] = f2bf((x2 * c2 + x1 * s2v) * sc);
}

// ---------------- RoPE for K (row-swizzled) + V transpose (block-swizzled) ----------------
__global__ void k_ropekv(const u16* __restrict__ qkv, const float* __restrict__ cs,
                         const float* __restrict__ sn, u16* __restrict__ Ksw,
                         u16* __restrict__ Vts) {
  int tid = threadIdx.x;
  int idx = blockIdx.x * 4 + (tid >> 6);
  int d = tid & 63;
  int kv = idx >> 11, s = idx & (S_ - 1);
  const u16* xk = qkv + (size_t)s * 3072 + 2048 + kv * 128;
  const u16* xv = xk + 512;
  float x1 = bf2f(xk[d]), x2 = bf2f(xk[d + 64]);
  float c1 = cs[s * D_ + d], s1v = sn[s * D_ + d];
  float c2 = cs[s * D_ + d + 64], s2v = sn[s * D_ + d + 64];
  u16* ko = Ksw + ((size_t)kv * S_ + s) * D_;
  int sw = (s & 7) << 3;
  ko[d ^ sw]        = f2bf(x1 * c1 - x2 * s1v);
  ko[(d + 64) ^ sw] = f2bf(x2 * c2 + x1 * s2v);
  // V: no rope; write transposed [D][S] with 64-key-block swizzle
  u16* vo = Vts + (size_t)kv * D_ * S_;
  int sc64 = s & ~63, sl = s & 63;
  vo[(size_t)d * S_        + sc64 + (sl ^ ((d & 7) << 3))] = xv[d];
  vo[(size_t)(d + 64) * S_ + sc64 + (sl ^ ((d & 7) << 3))] = xv[d + 64];
}

// ---------------- retrieval K/V convert: same swizzled layouts ----------------
__global__ void k_retr(const float* __restrict__ rk, const float* __restrict__ rv,
                       u16* __restrict__ Krs, u16* __restrict__ Vtrs) {
  int tid = threadIdx.x;
  int idx = blockIdx.x * 2 + (tid >> 7);
  int d = tid & 127;
  int kv = idx >> 11, r = idx & (RLEN_ - 1);
  size_t base = ((size_t)kv * RLEN_ + r) * D_;
  Krs[base + (d ^ ((r & 7) << 3))] = f2bf(rk[base + d]);
  int rc = r & ~63, rl = r & 63;
  Vtrs[((size_t)kv * D_ + d) * RLEN_ + rc + (rl ^ ((d & 7) << 3))] = f2bf(rv[base + d]);
}

// ---------------- fused causal + retrieval flash attention ----------------
// grid (32 chunks, 16 heads), 256 threads (4 waves x 16 q-rows)
__global__ __launch_bounds__(256) void k_attn(
    const u16* __restrict__ Q, const u16* __restrict__ Ksw, const u16* __restrict__ Vts,
    const u16* __restrict__ Krs, const u16* __restrict__ Vtrs, u16* __restrict__ Aout) {
  __shared__ __attribute__((aligned(16))) u16 Kl[64 * 128];   // swizzled K rows (256B rows)
  __shared__ __attribute__((aligned(16))) u16 Vl[128 * 64];   // swizzled V^T rows (128B rows)
  __shared__ __attribute__((aligned(16))) u16 Pl[4][16 * 64]; // per-wave P (swizzled 128B rows)
  const int c = blockIdx.x, h = blockIdx.y, kvh = h >> 2;
  const int tid = threadIdx.x, wave = tid >> 6, lane = tid & 63;
  const int l15 = lane & 15, lhi = lane >> 4;

  bf16x8 qf[4];
  {
    const u16* qp = Q + ((size_t)h * S_ + c * 64 + wave * 16 + l15) * D_ + lhi * 8;
#pragma unroll
    for (int kd = 0; kd < 4; kd++) qf[kd] = *(const bf16x8*)(qp + kd * 32);
  }
  float mrow[4] = {-1e30f, -1e30f, -1e30f, -1e30f};
  float lrow[4] = {0.f, 0.f, 0.f, 0.f};
  f32x4 acc[8] = {};

  const int ntiles = c + ((c >= 1) ? 2 : 1);
  for (int t = 0; t < ntiles; t++) {
    const bool isr = (t == c + 1);
    const u16* kb = isr ? (Krs + (size_t)kvh * RLEN_ * D_) : (Ksw + (size_t)kvh * S_ * D_);
    const u16* vb = isr ? (Vtrs + (size_t)kvh * D_ * RLEN_) : (Vts + (size_t)kvh * D_ * S_);
    const int vstr = isr ? RLEN_ : S_;
    const int k0 = isr ? (c - 1) * 64 : t * 64;

    __syncthreads();
#pragma unroll
    for (int p = 0; p < 4; p++) {
      int t2 = p * 256 + tid;
      GLL(kb + (size_t)(k0 + (t2 >> 4)) * D_ + (t2 & 15) * 8, Kl + p * 2048 + wave * 512);
      GLL(vb + (size_t)(t2 >> 3) * vstr + k0 + (t2 & 7) * 8,  Vl + p * 2048 + wave * 512);
    }
    __syncthreads();

    // scores: S = Q * K^T  (16q x 64k per wave)
    f32x4 scr[4];
#pragma unroll
    for (int n = 0; n < 4; n++) {
      f32x4 sa = {};
      const int key = n * 16 + l15;
#pragma unroll
      for (int kd = 0; kd < 4; kd++) {
        const int db = (kd * 64 + lhi * 16) ^ ((key & 7) << 4);
        bf16x8 kf = *(const bf16x8*)((const char*)Kl + key * 256 + db);
        sa = __builtin_amdgcn_mfma_f32_16x16x32_bf16(qf[kd], kf, sa, 0, 0, 0);
      }
      scr[n] = sa;
    }
    if (!isr && t == c) {  // diagonal tile: causal mask
#pragma unroll
      for (int n = 0; n < 4; n++) {
        const int kg = n * 16 + l15;
#pragma unroll
        for (int j = 0; j < 4; j++) {
          const int qg = wave * 16 + lhi * 4 + j;
          if (kg > qg) scr[n][j] = -1e30f;
        }
      }
    }
    // online softmax (rows live on 16-lane groups)
    float f[4];
#pragma unroll
    for (int j = 0; j < 4; j++) {
      float v = fmaxf(fmaxf(scr[0][j], scr[1][j]), fmaxf(scr[2][j], scr[3][j]));
      v = fmaxf(v, __shfl_xor(v, 1));
      v = fmaxf(v, __shfl_xor(v, 2));
      v = fmaxf(v, __shfl_xor(v, 4));
      v = fmaxf(v, __shfl_xor(v, 8));
      float mn = fmaxf(mrow[j], v);
      f[j] = __expf(mrow[j] - mn);
      mrow[j] = mn;
    }
    float rs[4] = {0.f, 0.f, 0.f, 0.f};
#pragma unroll
    for (int n = 0; n < 4; n++)
#pragma unroll
      for (int j = 0; j < 4; j++) {
        float p = __expf(scr[n][j] - mrow[j]);
        scr[n][j] = p;
        rs[j] += p;
      }
#pragma unroll
    for (int j = 0; j < 4; j++) {
      float v = rs[j];
      v += __shfl_xor(v, 1);
      v += __shfl_xor(v, 2);
      v += __shfl_xor(v, 4);
      v += __shfl_xor(v, 8);
      lrow[j] = lrow[j] * f[j] + v;
    }
#pragma unroll
    for (int nd = 0; nd < 8; nd++)
#pragma unroll
      for (int j = 0; j < 4; j++) acc[nd][j] *= f[j];
    // P -> LDS (bf16, swizzled rows)
#pragma unroll
    for (int n = 0; n < 4; n++)
#pragma unroll
      for (int j = 0; j < 4; j++) {
        const int q16 = lhi * 4 + j;
        const int key = n * 16 + l15;
        *(u16*)((char*)(&Pl[wave][0]) + q16 * 128 + ((key * 2) ^ ((q16 & 7) << 4))) =
            f2bf(scr[n][j]);
      }
    __syncthreads();
    // O += P * V
#pragma unroll
    for (int kk = 0; kk < 2; kk++) {
      const int pb = (kk * 64 + lhi * 16) ^ ((l15 & 7) << 4);
      bf16x8 pf = *(const bf16x8*)((const char*)(&Pl[wave][0]) + l15 * 128 + pb);
#pragma unroll
      for (int nd = 0; nd < 8; nd++) {
        const int dd = nd * 16 + l15;
        const int vby = (kk * 64 + lhi * 16) ^ ((dd & 7) << 4);
        bf16x8 vf = *(const bf16x8*)((const char*)Vl + dd * 128 + vby);
        acc[nd] = __builtin_amdgcn_mfma_f32_16x16x32_bf16(pf, vf, acc[nd], 0, 0, 0);
      }
    }
  }
  // epilogue: normalize + store bf16 [S][H*D]
#pragma unroll
  for (int nd = 0; nd < 8; nd++)
#pragma unroll
    for (int j = 0; j < 4; j++) {
      const int srow = c * 64 + wave * 16 + lhi * 4 + j;
      const int col = h * 128 + nd * 16 + l15;
      Aout[(size_t)srow * (H_ * D_) + col] = f2bf(acc[nd][j] / lrow[j]);
    }
}

extern "C" void kernel_launch(void* const* d_in, const int* in_sizes, int n_in,
                              void* d_out, int out_size, void* d_ws, size_t ws_size,
                              hipStream_t stream) {
  const float* hs = (const float*)d_in[0];
  const float* cs = (const float*)d_in[1];
  const float* sn = (const float*)d_in[2];
  const float* rk = (const float*)d_in[3];
  const float* rv = (const float*)d_in[4];
  const float* Wq = (const float*)d_in[5];
  const float* Wk = (const float*)d_in[6];
  const float* Wv = (const float*)d_in[7];
  const float* Wo = (const float*)d_in[8];
  float* out = (float*)d_out;
  char* ws = (char*)d_ws;
  if (ws_size < (size_t)(56u << 20)) return;  // fail visibly (output stays poisoned)

  u16* hsb  = (u16*)(ws);               // 8MB   hidden bf16 (reused as attn out later)
  u16* wtq  = (u16*)(ws + (8 << 20));   // 12MB  [Wq|Wk|Wv]^T  (3072 x 2048)
  u16* wto  = (u16*)(ws + (20 << 20));  // 8MB   Wo^T (2048 x 2048)
  u16* qkv  = (u16*)(ws + (28 << 20));  // 12MB  raw qkv (2048 x 3072)
  u16* Qr   = (u16*)(ws + (40 << 20));  // 8MB   roped+scaled Q [16][2048][128]
  u16* Ks   = (u16*)(ws + (48 << 20));  // 2MB   roped K swizzled [4][2048][128]
  u16* Vts  = (u16*)(ws + (50 << 20));  // 2MB   V^T swizzled [4][128][2048]
  u16* Krs  = (u16*)(ws + (52 << 20));  // 2MB   retrieval K swizzled
  u16* Vtrs = (u16*)(ws + (54 << 20));  // 2MB   retrieval V^T swizzled
  u16* attn = hsb;                      // safe reuse: hs consumed by gemm1

  k_cvt<<<4096, 256, 0, stream>>>(hs, hsb, 1048576);
  dim3 tb(32, 8);
  k_transw<<<dim3(64, 64), tb, 0, stream>>>(Wq, wtq, 2048, 2048);
  k_transw<<<dim3(16, 64), tb, 0, stream>>>(Wk, wtq + (size_t)2048 * 2048, 2048, 512);
  k_transw<<<dim3(16, 64), tb, 0, stream>>>(Wv, wtq + (size_t)2560 * 2048, 2048, 512);
  k_transw<<<dim3(64, 64), tb, 0, stream>>>(Wo, wto, 2048, 2048);
  k_gemm<0><<<dim3(24, 16), 256, 0, stream>>>(hsb, wtq, nullptr, qkv, 2048, 3072, 2048);
  k_ropeq<<<8192, 256, 0, stream>>>(qkv, cs, sn, Qr);
  k_ropekv<<<2048, 256, 0, stream>>>(qkv, cs, sn, Ks, Vts);
  k_retr<<<4096, 256, 0, stream>>>(rk, rv, Krs, Vtrs);
  k_attn<<<dim3(32, 16), 256, 0, stream>>>(Qr, Ks, Vts, Krs, Vtrs, attn);
  k_gemm<1><<<dim3(16, 16), 256, 0, stream>>>(attn, wto, out, nullptr, 2048, 2048, 2048);
}

// Round 2
// 219.688 us; speedup vs baseline: 1.0915x; 1.0915x over previous
//
#include <hip/hip_runtime.h>
#include <stdint.h>

#define H_    16
#define HKV_  4
#define D_    128
#define S_    2048
#define HID_  2048
#define RLEN_ 2048

typedef unsigned short u16;
typedef __attribute__((ext_vector_type(4))) float f32x4;
typedef __attribute__((ext_vector_type(8))) __bf16 bf16x8;
typedef __attribute__((ext_vector_type(4))) unsigned short u16x4;
typedef __attribute__((ext_vector_type(8))) unsigned short u16x8;

__device__ __forceinline__ u16 f2bf(float f) {
  union { float f; unsigned u; } v; v.f = f;
  unsigned r = v.u + 0x7FFFu + ((v.u >> 16) & 1u);
  return (u16)(r >> 16);
}
__device__ __forceinline__ float bf2f(u16 h) {
  union { unsigned u; float f; } v; v.u = ((unsigned)h) << 16;
  return v.f;
}

#define GLL(srcp, ldsp) \
  __builtin_amdgcn_global_load_lds((const __attribute__((address_space(1))) unsigned int*)(srcp), \
                                   (__attribute__((address_space(3))) unsigned int*)(ldsp), 16, 0, 0)

// ---------------- fp32 -> bf16 elementwise ----------------
__global__ void k_cvt(const float* __restrict__ in, u16* __restrict__ out, int n4) {
  int i = blockIdx.x * 256 + threadIdx.x;
  if (i >= n4) return;
  float4 v = ((const float4*)in)[i];
  u16x4 o;
  o.x = f2bf(v.x); o.y = f2bf(v.y); o.z = f2bf(v.z); o.w = f2bf(v.w);
  ((u16x4*)out)[i] = o;
}

// ---------------- fp32 (K x N) -> bf16 transposed (N x K) ----------------
__global__ void k_transw(const float* __restrict__ in, u16* __restrict__ out, int K, int N) {
  __shared__ float tile[32][33];
  int bx = blockIdx.x * 32, by = blockIdx.y * 32;
  int tx = threadIdx.x, ty = threadIdx.y;  // 32 x 8
#pragma unroll
  for (int i = 0; i < 32; i += 8)
    tile[ty + i][tx] = in[(size_t)(by + ty + i) * N + bx + tx];
  __syncthreads();
#pragma unroll
  for (int i = 0; i < 32; i += 8)
    out[(size_t)(bx + ty + i) * K + by + tx] = f2bf(tile[tx][ty + i]);
}

// ---------------- bf16 GEMM: C = A(MxK) * Bt(NxK)^T ; m97 structure ----------------
template <int OUTF32>
__global__ __launch_bounds__(256) void k_gemm(const u16* __restrict__ A, const u16* __restrict__ Bt,
                                              float* __restrict__ Cf, u16* __restrict__ Cb,
                                              int M, int N, int K) {
  __shared__ __attribute__((aligned(16))) u16 As[128 * 32];
  __shared__ __attribute__((aligned(16))) u16 Bs[128 * 32];
  const int bm = blockIdx.y * 128, bn = blockIdx.x * 128;
  const int tid = threadIdx.x, wave = tid >> 6, lane = tid & 63;
  const int wr = wave >> 1, wc = wave & 1;
  const int l15 = lane & 15, lhi = lane >> 4;
  f32x4 acc[4][4] = {};
  const u16* pA  = A  + (size_t)(bm + (tid >> 2)) * K + (tid & 3) * 8;
  const u16* pA2 = A  + (size_t)(bm + 64 + (tid >> 2)) * K + (tid & 3) * 8;
  const u16* pB  = Bt + (size_t)(bn + (tid >> 2)) * K + (tid & 3) * 8;
  const u16* pB2 = Bt + (size_t)(bn + 64 + (tid >> 2)) * K + (tid & 3) * 8;

  for (int k0 = 0; k0 < K; k0 += 32) {
    __syncthreads();
    GLL(pA + k0,  As + wave * 512);
    GLL(pA2 + k0, As + 2048 + wave * 512);
    GLL(pB + k0,  Bs + wave * 512);
    GLL(pB2 + k0, Bs + 2048 + wave * 512);
    __syncthreads();
    bf16x8 af[4], bfr[4];
#pragma unroll
    for (int m = 0; m < 4; m++)
      af[m] = *(const bf16x8*)(As + (wr * 64 + m * 16 + l15) * 32 + lhi * 8);
#pragma unroll
    for (int n = 0; n < 4; n++)
      bfr[n] = *(const bf16x8*)(Bs + (wc * 64 + n * 16 + l15) * 32 + lhi * 8);
#pragma unroll
    for (int m = 0; m < 4; m++)
#pragma unroll
      for (int n = 0; n < 4; n++)
        acc[m][n] = __builtin_amdgcn_mfma_f32_16x16x32_bf16(af[m], bfr[n], acc[m][n], 0, 0, 0);
  }
  const int r0 = bm + wr * 64, c0 = bn + wc * 64;
#pragma unroll
  for (int m = 0; m < 4; m++)
#pragma unroll
    for (int n = 0; n < 4; n++) {
      int r = r0 + m * 16 + lhi * 4, cc = c0 + n * 16 + l15;
#pragma unroll
      for (int j = 0; j < 4; j++) {
        if (OUTF32) Cf[(size_t)(r + j) * N + cc] = acc[m][n][j];
        else        Cb[(size_t)(r + j) * N + cc] = f2bf(acc[m][n][j]);
      }
    }
}

// ---------------- RoPE for Q (scale folded in), plain [H][S][D] layout ----------------
__global__ void k_ropeq(const u16* __restrict__ qkv, const float* __restrict__ cs,
                        const float* __restrict__ sn, u16* __restrict__ Q) {
  int tid = threadIdx.x;
  int idx = blockIdx.x * 4 + (tid >> 6);
  int d = tid & 63;
  int h = idx >> 11, s = idx & (S_ - 1);
  const u16* x = qkv + (size_t)s * 3072 + h * 128;
  float x1 = bf2f(x[d]), x2 = bf2f(x[d + 64]);
  float c1 = cs[s * D_ + d], s1v = sn[s * D_ + d];
  float c2 = cs[s * D_ + d + 64], s2v = sn[s * D_ + d + 64];
  const float sc = 0.08838834764831845f;  // D^-0.5
  u16* o = Q + ((size_t)h * S_ + s) * D_;
  o[d]      = f2bf((x1 * c1 - x2 * s1v) * sc);
  o[d + 64] = f2bf((x2 * c2 + x1 * s2v) * sc);
}

// ---------------- RoPE for K (row-swizzled) + V transpose (block-swizzled) ----------------
__global__ void k_ropekv(const u16* __restrict__ qkv, const float* __restrict__ cs,
                         const float* __restrict__ sn, u16* __restrict__ Ksw,
                         u16* __restrict__ Vts) {
  int tid = threadIdx.x;
  int idx = blockIdx.x * 4 + (tid >> 6);
  int d = tid & 63;
  int kv = idx >> 11, s = idx & (S_ - 1);
  const u16* xk = qkv + (size_t)s * 3072 + 2048 + kv * 128;
  const u16* xv = xk + 512;
  float x1 = bf2f(xk[d]), x2 = bf2f(xk[d + 64]);
  float c1 = cs[s * D_ + d], s1v = sn[s * D_ + d];
  float c2 = cs[s * D_ + d + 64], s2v = sn[s * D_ + d + 64];
  u16* ko = Ksw + ((size_t)kv * S_ + s) * D_;
  int sw = (s & 7) << 3;
  ko[d ^ sw]        = f2bf(x1 * c1 - x2 * s1v);
  ko[(d + 64) ^ sw] = f2bf(x2 * c2 + x1 * s2v);
  // V: no rope; write transposed [D][S] with 64-key-block swizzle
  u16* vo = Vts + (size_t)kv * D_ * S_;
  int sc64 = s & ~63, sl = s & 63;
  vo[(size_t)d * S_        + sc64 + (sl ^ ((d & 7) << 3))] = xv[d];
  vo[(size_t)(d + 64) * S_ + sc64 + (sl ^ ((d & 7) << 3))] = xv[d + 64];
}

// ---------------- retrieval K/V convert: same swizzled layouts ----------------
__global__ void k_retr(const float* __restrict__ rk, const float* __restrict__ rv,
                       u16* __restrict__ Krs, u16* __restrict__ Vtrs) {
  int tid = threadIdx.x;
  int idx = blockIdx.x * 2 + (tid >> 7);
  int d = tid & 127;
  int kv = idx >> 11, r = idx & (RLEN_ - 1);
  size_t base = ((size_t)kv * RLEN_ + r) * D_;
  Krs[base + (d ^ ((r & 7) << 3))] = f2bf(rk[base + d]);
  int rc = r & ~63, rl = r & 63;
  Vtrs[((size_t)kv * D_ + d) * RLEN_ + rc + (rl ^ ((d & 7) << 3))] = f2bf(rv[base + d]);
}

// ---------------- fused causal + retrieval flash attention, split-K ----------------
// grid (84 partition entries, 16 heads), 256 threads (4 waves x 16 q-rows).
// Each block computes a balanced slice of the key-tile range for one (head, chunk)
// and writes unnormalized partial O (bf16) + per-row (m, l) for k_combine.
__global__ __launch_bounds__(256) void k_attn(
    const u16* __restrict__ Q, const u16* __restrict__ Ksw, const u16* __restrict__ Vts,
    const u16* __restrict__ Krs, const u16* __restrict__ Vtrs,
    u16* __restrict__ Opart, float* __restrict__ Ml) {
  __shared__ __attribute__((aligned(16))) u16 Kl[64 * 128];   // swizzled K rows (256B rows)
  __shared__ __attribute__((aligned(16))) u16 Vl[128 * 64];   // swizzled V^T rows (128B rows)
  __shared__ __attribute__((aligned(16))) u16 Pl[4][16 * 64]; // per-wave P (swizzled 128B rows)
  const int e = blockIdx.x, h = blockIdx.y, kvh = h >> 2;
  // partition table: chunk c has nt = (c==0?1:c+2) tiles, split into ceil(nt/8) parts
  int c, part, np;
  if (e < 7)       { c = e;               part = 0;           np = 1; }
  else if (e < 23) { c = 7 + ((e - 7) >> 1);  part = (e - 7) & 1;  np = 2; }
  else if (e < 47) { c = 15 + (e - 23) / 3;   part = (e - 23) % 3; np = 3; }
  else if (e < 79) { c = 23 + ((e - 47) >> 2); part = (e - 47) & 3; np = 4; }
  else             { c = 31;              part = e - 79;      np = 5; }
  const int nt = (c == 0) ? 1 : (c + 2);
  const int t0 = (part * nt) / np, t1 = ((part + 1) * nt) / np;
  const int bp = h * 84 + e;

  const int tid = threadIdx.x, wave = tid >> 6, lane = tid & 63;
  const int l15 = lane & 15, lhi = lane >> 4;

  bf16x8 qf[4];
  {
    const u16* qp = Q + ((size_t)h * S_ + c * 64 + wave * 16 + l15) * D_ + lhi * 8;
#pragma unroll
    for (int kd = 0; kd < 4; kd++) qf[kd] = *(const bf16x8*)(qp + kd * 32);
  }
  float mrow[4] = {-1e30f, -1e30f, -1e30f, -1e30f};
  float lrow[4] = {0.f, 0.f, 0.f, 0.f};
  f32x4 acc[8] = {};

  for (int t = t0; t < t1; t++) {
    const bool isr = (t == c + 1);
    const u16* kb = isr ? (Krs + (size_t)kvh * RLEN_ * D_) : (Ksw + (size_t)kvh * S_ * D_);
    const u16* vb = isr ? (Vtrs + (size_t)kvh * D_ * RLEN_) : (Vts + (size_t)kvh * D_ * S_);
    const int vstr = isr ? RLEN_ : S_;
    const int k0 = isr ? (c - 1) * 64 : t * 64;

    __syncthreads();
#pragma unroll
    for (int p = 0; p < 4; p++) {
      int t2 = p * 256 + tid;
      GLL(kb + (size_t)(k0 + (t2 >> 4)) * D_ + (t2 & 15) * 8, Kl + p * 2048 + wave * 512);
      GLL(vb + (size_t)(t2 >> 3) * vstr + k0 + (t2 & 7) * 8,  Vl + p * 2048 + wave * 512);
    }
    __syncthreads();

    // scores: S = Q * K^T  (16q x 64k per wave)
    f32x4 scr[4];
#pragma unroll
    for (int n = 0; n < 4; n++) {
      f32x4 sa = {};
      const int key = n * 16 + l15;
#pragma unroll
      for (int kd = 0; kd < 4; kd++) {
        const int db = (kd * 64 + lhi * 16) ^ ((key & 7) << 4);
        bf16x8 kf = *(const bf16x8*)((const char*)Kl + key * 256 + db);
        sa = __builtin_amdgcn_mfma_f32_16x16x32_bf16(qf[kd], kf, sa, 0, 0, 0);
      }
      scr[n] = sa;
    }
    if (!isr && t == c) {  // diagonal tile: causal mask
#pragma unroll
      for (int n = 0; n < 4; n++) {
        const int kg = n * 16 + l15;
#pragma unroll
        for (int j = 0; j < 4; j++) {
          const int qg = wave * 16 + lhi * 4 + j;
          if (kg > qg) scr[n][j] = -1e30f;
        }
      }
    }
    // online softmax (rows live on 16-lane groups)
    float f[4];
#pragma unroll
    for (int j = 0; j < 4; j++) {
      float v = fmaxf(fmaxf(scr[0][j], scr[1][j]), fmaxf(scr[2][j], scr[3][j]));
      v = fmaxf(v, __shfl_xor(v, 1));
      v = fmaxf(v, __shfl_xor(v, 2));
      v = fmaxf(v, __shfl_xor(v, 4));
      v = fmaxf(v, __shfl_xor(v, 8));
      float mn = fmaxf(mrow[j], v);
      f[j] = __expf(mrow[j] - mn);
      mrow[j] = mn;
    }
    float rs[4] = {0.f, 0.f, 0.f, 0.f};
#pragma unroll
    for (int n = 0; n < 4; n++)
#pragma unroll
      for (int j = 0; j < 4; j++) {
        float p = __expf(scr[n][j] - mrow[j]);
        scr[n][j] = p;
        rs[j] += p;
      }
#pragma unroll
    for (int j = 0; j < 4; j++) {
      float v = rs[j];
      v += __shfl_xor(v, 1);
      v += __shfl_xor(v, 2);
      v += __shfl_xor(v, 4);
      v += __shfl_xor(v, 8);
      lrow[j] = lrow[j] * f[j] + v;
    }
#pragma unroll
    for (int nd = 0; nd < 8; nd++)
#pragma unroll
      for (int j = 0; j < 4; j++) acc[nd][j] *= f[j];
    // P -> LDS (bf16, swizzled rows); per-wave buffer, no cross-wave barrier needed
#pragma unroll
    for (int n = 0; n < 4; n++)
#pragma unroll
      for (int j = 0; j < 4; j++) {
        const int q16 = lhi * 4 + j;
        const int key = n * 16 + l15;
        *(u16*)((char*)(&Pl[wave][0]) + q16 * 128 + ((key * 2) ^ ((q16 & 7) << 4))) =
            f2bf(scr[n][j]);
      }
    // O += P * V
#pragma unroll
    for (int kk = 0; kk < 2; kk++) {
      const int pb = (kk * 64 + lhi * 16) ^ ((l15 & 7) << 4);
      bf16x8 pf = *(const bf16x8*)((const char*)(&Pl[wave][0]) + l15 * 128 + pb);
#pragma unroll
      for (int nd = 0; nd < 8; nd++) {
        const int dd = nd * 16 + l15;
        const int vby = (kk * 64 + lhi * 16) ^ ((dd & 7) << 4);
        bf16x8 vf = *(const bf16x8*)((const char*)Vl + dd * 128 + vby);
        acc[nd] = __builtin_amdgcn_mfma_f32_16x16x32_bf16(pf, vf, acc[nd], 0, 0, 0);
      }
    }
  }
  // epilogue: write unnormalized partial O (bf16) + per-row m, l
  u16* op = Opart + (size_t)bp * 8192;
#pragma unroll
  for (int nd = 0; nd < 8; nd++)
#pragma unroll
    for (int j = 0; j < 4; j++) {
      const int q = wave * 16 + lhi * 4 + j;
      op[q * 128 + nd * 16 + l15] = f2bf(acc[nd][j]);
    }
  if (l15 == 0) {
#pragma unroll
    for (int j = 0; j < 4; j++) {
      const int q = wave * 16 + lhi * 4 + j;
      Ml[(size_t)bp * 128 + q]      = mrow[j];
      Ml[(size_t)bp * 128 + 64 + q] = lrow[j];
    }
  }
}

// ---------------- split-K combine: merge <=5 partials per (head, chunk) ----------------
__global__ __launch_bounds__(256) void k_combine(const u16* __restrict__ Opart,
                                                 const float* __restrict__ Ml,
                                                 u16* __restrict__ attn) {
  const int c = blockIdx.x, h = blockIdx.y;
  const int t = threadIdx.x;
  const int q = t >> 2, d0 = (t & 3) * 32;
  int base, np;
  if (c < 7)       { base = c;                 np = 1; }
  else if (c < 15) { base = 7 + 2 * (c - 7);   np = 2; }
  else if (c < 23) { base = 23 + 3 * (c - 15); np = 3; }
  else if (c < 31) { base = 47 + 4 * (c - 23); np = 4; }
  else             { base = 79;                np = 5; }
  const size_t pb = (size_t)h * 84 + base;

  float m = -1e30f;
  for (int p = 0; p < np; p++) m = fmaxf(m, Ml[(pb + p) * 128 + q]);
  float l = 0.f;
  float N[32];
#pragma unroll
  for (int i = 0; i < 32; i++) N[i] = 0.f;
  for (int p = 0; p < np; p++) {
    const float mp = Ml[(pb + p) * 128 + q];
    const float lp = Ml[(pb + p) * 128 + 64 + q];
    const float w = __expf(mp - m);
    l += w * lp;
    const u16* op = Opart + (pb + p) * 8192 + q * 128 + d0;
#pragma unroll
    for (int i = 0; i < 4; i++) {
      u16x8 v = ((const u16x8*)op)[i];
#pragma unroll
      for (int ee = 0; ee < 8; ee++) N[i * 8 + ee] += w * bf2f(v[ee]);
    }
  }
  const float inv = 1.f / l;
  u16* dst = attn + (size_t)(c * 64 + q) * (H_ * D_) + h * 128 + d0;
#pragma unroll
  for (int i = 0; i < 4; i++) {
    u16x8 o;
#pragma unroll
    for (int ee = 0; ee < 8; ee++) o[ee] = f2bf(N[i * 8 + ee] * inv);
    ((u16x8*)dst)[i] = o;
  }
}

extern "C" void kernel_launch(void* const* d_in, const int* in_sizes, int n_in,
                              void* d_out, int out_size, void* d_ws, size_t ws_size,
                              hipStream_t stream) {
  const float* hs = (const float*)d_in[0];
  const float* cs = (const float*)d_in[1];
  const float* sn = (const float*)d_in[2];
  const float* rk = (const float*)d_in[3];
  const float* rv = (const float*)d_in[4];
  const float* Wq = (const float*)d_in[5];
  const float* Wk = (const float*)d_in[6];
  const float* Wv = (const float*)d_in[7];
  const float* Wo = (const float*)d_in[8];
  float* out = (float*)d_out;
  char* ws = (char*)d_ws;
  if (ws_size < (size_t)(56u << 20)) return;  // fail visibly (output stays poisoned)

  u16* hsb  = (u16*)(ws);                 // 8MB  hidden bf16 (reused as attn out later)
  u16* wto  = (u16*)(ws + (8u << 20));    // 8MB  Wo^T
  u16* Qr   = (u16*)(ws + (16u << 20));   // 8MB  roped+scaled Q [16][2048][128]
  u16* Ks   = (u16*)(ws + (24u << 20));   // 2MB  roped K swizzled
  u16* Vts  = (u16*)(ws + (26u << 20));   // 2MB  V^T swizzled
  u16* Krs  = (u16*)(ws + (28u << 20));   // 2MB  retrieval K swizzled
  u16* Vtrs = (u16*)(ws + (30u << 20));   // 2MB  retrieval V^T swizzled
  u16* wtq  = (u16*)(ws + (32u << 20));   // 12MB [Wq|Wk|Wv]^T (phase 1 only)
  u16* qkv  = (u16*)(ws + (44u << 20));   // 12MB raw qkv (phase 1 only)
  u16* Opart= (u16*)(ws + (32u << 20));   // 21MB split-K partial O (phase 2, aliases wtq/qkv)
  float* Ml = (float*)(ws + (54u << 20)); // 0.7MB per-row (m, l)
  u16* attn = hsb;                        // safe reuse: hs consumed by gemm1

  k_cvt<<<4096, 256, 0, stream>>>(hs, hsb, 1048576);
  dim3 tb(32, 8);
  k_transw<<<dim3(64, 64), tb, 0, stream>>>(Wq, wtq, 2048, 2048);
  k_transw<<<dim3(16, 64), tb, 0, stream>>>(Wk, wtq + (size_t)2048 * 2048, 2048, 512);
  k_transw<<<dim3(16, 64), tb, 0, stream>>>(Wv, wtq + (size_t)2560 * 2048, 2048, 512);
  k_transw<<<dim3(64, 64), tb, 0, stream>>>(Wo, wto, 2048, 2048);
  k_gemm<0><<<dim3(24, 16), 256, 0, stream>>>(hsb, wtq, nullptr, qkv, 2048, 3072, 2048);
  k_ropeq<<<8192, 256, 0, stream>>>(qkv, cs, sn, Qr);
  k_ropekv<<<2048, 256, 0, stream>>>(qkv, cs, sn, Ks, Vts);
  k_retr<<<4096, 256, 0, stream>>>(rk, rv, Krs, Vtrs);
  k_attn<<<dim3(84, 16), 256, 0, stream>>>(Qr, Ks, Vts, Krs, Vtrs, Opart, Ml);
  k_combine<<<dim3(32, 16), 256, 0, stream>>>(Opart, Ml, attn);
  k_gemm<1><<<dim3(16, 16), 256, 0, stream>>>(attn, wto, out, nullptr, 2048, 2048, 2048);
}